// Round 1
// baseline (393.662 us; speedup 1.0000x reference)
//
#include <hip/hip_runtime.h>
#include <hip/hip_bf16.h>
#include <math.h>

#define KMAX 45
#define RAD  22
#define TH   16
#define TSTRIDE 321   // 16-row LDS stride; 321 % 32 == 1 -> conflict-free horiz reads
#define PADL 32       // logical col c maps to LDS col c+PADL

// ---------------- top-k (rank by count) + sigmoid(lambda) ----------------
__global__ __launch_bounds__(128) void gmix_topk(const float* __restrict__ cp,
                                                 const float* __restrict__ lp,
                                                 int* __restrict__ idx,
                                                 float* __restrict__ lam) {
    int i = threadIdx.x;
    if (i < 90) {
        float v = cp[i];
        int rank = 0;
        for (int j = 0; j < 90; ++j) {
            float vj = cp[j];
            rank += (vj > v) || (vj == v && j < i);
        }
        if (rank < 64) idx[rank] = i;
    }
    if (i == 0) {
        lam[0] = 1.0f / (1.0f + expf(-lp[0]));
    }
}

// ---------------- fused separable conv + clip + mix ----------------
// grid: 32 pairs * 12 planes * 16 row-tiles = 6144 blocks, 256 threads
__global__ __launch_bounds__(256) void gmix_conv(const float* __restrict__ img,
                                                 const float* __restrict__ kers,
                                                 const int* __restrict__ idx,
                                                 const float* __restrict__ lamp,
                                                 float* __restrict__ out) {
    __shared__ float tmp[TH * TSTRIDE];

    const int tid   = threadIdx.x;
    const int bid   = blockIdx.x;
    const int p     = bid / 192;          // pair
    const int rem   = bid % 192;
    const int plane = rem / 16;           // b*3+c
    const int tile  = rem % 16;
    const int r0    = tile * TH;

    const float* imgp = img + (size_t)plane * 65536;
    const float  lam  = lamp[0];
    const int fA = idx[2 * p];
    const int fB = idx[2 * p + 1];

    // zero LDS (pads stay zero for both filters; interior is overwritten)
    for (int z = tid; z < TH * TSTRIDE; z += 256) tmp[z] = 0.f;

    float res[16];
#pragma unroll
    for (int j = 0; j < 16; ++j) res[j] = 0.f;

    const int hr   = tid & 15;            // horizontal-pass row
    const int hseg = tid >> 4;            // horizontal-pass 16-col segment

#pragma unroll 1
    for (int fi = 0; fi < 2; ++fi) {
        const int   f   = (fi == 0) ? fA : fB;
        const float wgt = (fi == 0) ? lam : 1.0f - lam;
        const int   w   = 5 * (f / 10 + 1);      // true filter width
        const int   off = (KMAX - w) / 2;        // first nonzero tap
        const int   ilo = off;                   // first useful stream index
        const int   ihi = off + w + 14;          // last useful stream index

        // taps -> registers (uniform loads, all later indexing is static)
        float tap[KMAX];
#pragma unroll
        for (int k = 0; k < KMAX; ++k) tap[k] = kers[f * KMAX + k];

        // ---- vertical pass: thread = column tid, rows r0..r0+15 ----
        float acc[TH];
#pragma unroll
        for (int j = 0; j < TH; ++j) acc[j] = 0.f;

#pragma unroll
        for (int i = 0; i < 60; ++i) {
            if (i >= ilo && i <= ihi) {          // uniform branch (skip zero-tap iters)
                const int gr = r0 - RAD + i;
                float v = 0.f;
                if (gr >= 0 && gr < 256) v = imgp[gr * 256 + tid];
#pragma unroll
                for (int j = 0; j < TH; ++j) {
                    const int k = i - j;                 // static
                    if (k >= 0 && k < KMAX) acc[j] += tap[k] * v;
                }
            }
        }

        __syncthreads();   // (fi=0: after LDS zero-init; fi=1: after prev horiz reads)
#pragma unroll
        for (int j = 0; j < TH; ++j) tmp[j * TSTRIDE + PADL + tid] = acc[j];
        __syncthreads();

        // ---- horizontal pass: thread = (row hr, 16-col segment hseg) ----
        const int base = hr * TSTRIDE + hseg * 16 + (PADL - RAD);
        float acc2[16];
#pragma unroll
        for (int j = 0; j < 16; ++j) acc2[j] = 0.f;

#pragma unroll
        for (int i = 0; i < 60; ++i) {
            if (i >= ilo && i <= ihi) {
                const float v = tmp[base + i];
#pragma unroll
                for (int j = 0; j < 16; ++j) {
                    const int k = i - j;                 // static
                    if (k >= 0 && k < KMAX) acc2[j] += tap[k] * v;
                }
            }
        }

        // ---- combine: res += wgt * clip(img - low, -1, 1) ----
        const int grow = r0 + hr;
        const int gcol = hseg * 16;
#pragma unroll
        for (int j4 = 0; j4 < 4; ++j4) {
            const float4 iv = *reinterpret_cast<const float4*>(
                &imgp[grow * 256 + gcol + j4 * 4]);
            const float vals[4] = {iv.x, iv.y, iv.z, iv.w};
#pragma unroll
            for (int q = 0; q < 4; ++q) {
                float h = vals[q] - acc2[j4 * 4 + q];
                h = fminf(fmaxf(h, -1.f), 1.f);
                res[j4 * 4 + q] += wgt * h;
            }
        }
    }

    // ---- write output tile: out[p][plane][r0+hr][gcol..gcol+15] ----
    float* outp = out + (((size_t)(p * 12 + plane) * 256 + r0 + hr) * 256 + (hseg * 16));
#pragma unroll
    for (int j4 = 0; j4 < 4; ++j4) {
        float4 o = make_float4(res[j4 * 4 + 0], res[j4 * 4 + 1],
                               res[j4 * 4 + 2], res[j4 * 4 + 3]);
        *reinterpret_cast<float4*>(&outp[j4 * 4]) = o;
    }
}

extern "C" void kernel_launch(void* const* d_in, const int* in_sizes, int n_in,
                              void* d_out, int out_size, void* d_ws, size_t ws_size,
                              hipStream_t stream) {
    const float* image   = (const float*)d_in[0];   // [4,3,256,256]
    const float* kernels = (const float*)d_in[1];   // [90,45]
    const float* prompt  = (const float*)d_in[2];   // [90]
    const float* lambdap = (const float*)d_in[3];   // [1]
    float* out = (float*)d_out;                     // [32,4,3,256,256]

    int*   ws_idx = (int*)d_ws;                     // 64 ints
    float* ws_lam = (float*)((char*)d_ws + 256);    // 1 float

    gmix_topk<<<1, 128, 0, stream>>>(prompt, lambdap, ws_idx, ws_lam);
    gmix_conv<<<6144, 256, 0, stream>>>(image, kernels, ws_idx, ws_lam, out);
}

// Round 2
// 100.045 us; speedup vs baseline: 3.9348x; 3.9348x over previous
//
#include <hip/hip_runtime.h>
#include <hip/hip_bf16.h>
#include <math.h>

typedef __attribute__((ext_vector_type(8))) short bf16x8;
typedef __attribute__((ext_vector_type(4))) float f32x4;

#define IST 312                 // img LDS row stride (halfs), 624B: 16B-aligned rows, banks spread
#define HST 136                 // H_T row stride (halfs), 272B: 16B-aligned, banks spread
#define HT_OFF (112 * IST)      // half-index where H_T starts (byte 69,888)
#define TAP_BYTE_OFF 139520     // img 69,888 + H_T 69,632
#define LDS_BYTES 139904        // + taps 2*48*4

__device__ __forceinline__ unsigned short f2bf(float f) {
    unsigned u = __builtin_bit_cast(unsigned, f);
    u += 0x7FFFu + ((u >> 16) & 1u);          // RNE
    return (unsigned short)(u >> 16);
}

// ---------------- top-k (rank by count) + sigmoid(lambda) ----------------
__global__ __launch_bounds__(128) void gmix_topk(const float* __restrict__ cp,
                                                 const float* __restrict__ lp,
                                                 int* __restrict__ idx,
                                                 float* __restrict__ lam) {
    int i = threadIdx.x;
    if (i < 90) {
        float v = cp[i];
        int rank = 0;
        for (int j = 0; j < 90; ++j) {
            float vj = cp[j];
            rank += (vj > v) || (vj == v && j < i);
        }
        if (rank < 64) idx[rank] = i;
    }
    if (i == 0) lam[0] = 1.0f / (1.0f + expf(-lp[0]));
}

// ---------------- MFMA separable conv + clip + mix ----------------
// grid: 32 pairs * 12 planes * 4 row-bands = 1536 blocks, 512 threads (8 waves)
__global__ __launch_bounds__(512, 2) void gmix_mfma(const float* __restrict__ img,
                                                    const float* __restrict__ kers,
                                                    const int* __restrict__ idx,
                                                    const float* __restrict__ lamp,
                                                    float* __restrict__ out) {
    extern __shared__ char lds_raw[];
    short* S = (short*)lds_raw;                       // half-element view
    float* taps = (float*)(lds_raw + TAP_BYTE_OFF);   // [2][48]

    const int tid  = threadIdx.x;
    const int lane = tid & 63;
    const int wv   = tid >> 6;
    const int lm   = lane & 15;        // M/N sub-index
    const int lg   = lane >> 4;        // K-subgroup 0..3

    const int bid   = blockIdx.x;
    const int p     = bid / 48;
    const int rem   = bid % 48;
    const int plane = rem >> 2;
    const int band  = rem & 3;
    const int r0    = band * 64;

    const float* imgp = img + (size_t)plane * 65536;
    float* outbase = out;
    const int   fA  = idx[2 * p];
    const int   fB  = idx[2 * p + 1];
    const float lam = lamp[0];

    // ---- zero img LDS region (zero halo rows/cols are the SAME padding) ----
    {
        unsigned long long* Z = (unsigned long long*)lds_raw;
        for (int z = tid; z < (112 * IST * 2) / 8; z += 512) Z[z] = 0ull;
    }
    if (tid < 90) {
        int fi = tid / 45, k = tid % 45;
        int f  = fi ? fB : fA;
        taps[fi * 48 + k] = kers[f * 45 + k];
    }
    __syncthreads();

    // ---- stage image window rows [r0-22, r0+85] -> LDS bf16, col g -> g+24 ----
    for (int it = tid; it < 112 * 64; it += 512) {
        const int wr  = it >> 6;
        const int seg = it & 63;
        const int gr  = r0 - 22 + wr;
        if (gr >= 0 && gr < 256) {
            const float4 v = *(const float4*)(imgp + gr * 256 + seg * 4);
            uint2 pk;
            pk.x = (unsigned)f2bf(v.x) | ((unsigned)f2bf(v.y) << 16);
            pk.y = (unsigned)f2bf(v.z) | ((unsigned)f2bf(v.w) << 16);
            *(uint2*)(S + wr * IST + 24 + seg * 4) = pk;
        }
    }
    __syncthreads();

    float lowsA[4][2][4];   // saved filter-A vertical results [t][c2i][q]

#pragma unroll 1
    for (int fi = 0; fi < 2; ++fi) {
        // ---- build banded tap fragments (bf16) ----
        // B1[i,j] = tap[i-j-2] (pass1, window start c*16-24); B2[k,n] = tap[k-n] (pass2)
        bf16x8 b1[2], b2[2];
#pragma unroll
        for (int ka = 0; ka < 2; ++ka) {
            bf16x8 v1, v2;
#pragma unroll
            for (int e = 0; e < 8; ++e) {
                const int k  = ka * 32 + lg * 8 + e;
                const int d1 = k - lm - 2;
                const int d2 = k - lm;
                v1[e] = (d1 >= 0 && d1 < 45) ? (short)f2bf(taps[fi * 48 + d1]) : (short)0;
                v2[e] = (d2 >= 0 && d2 < 45) ? (short)f2bf(taps[fi * 48 + d2]) : (short)0;
            }
            b1[ka] = v1;
            b2[ka] = v2;
        }

        // ---- pass 1 (horizontal): H[rows 0..111][cols] -> H_T (transposed, bf16) ----
        // jobs: 7 row-tiles x 16 col-chunks = 112, 14 per wave
#pragma unroll 1
        for (int jl = 0; jl < 14; ++jl) {
            const int jj = wv * 14 + jl;
            const int t1 = jj >> 4;
            const int c  = jj & 15;
            const int arow  = t1 * 16 + lm;
            const int kbase = c * 16 + lg * 8;
            const bf16x8 a0 = *(const bf16x8*)(S + arow * IST + kbase);
            const bf16x8 a1 = *(const bf16x8*)(S + arow * IST + kbase + 32);
            f32x4 acc = {0.f, 0.f, 0.f, 0.f};
            acc = __builtin_amdgcn_mfma_f32_16x16x32_bf16(a0, b1[0], acc, 0, 0, 0);
            acc = __builtin_amdgcn_mfma_f32_16x16x32_bf16(a1, b1[1], acc, 0, 0, 0);
            // C: H row = t1*16 + lg*4 + q, H col = c*16 + lm  -> H_T[col][row], 4 contiguous halfs
            const int hrow = t1 * 16 + lg * 4;
            const int hcol = c * 16 + lm;
            unsigned long long pk =
                (unsigned long long)f2bf(acc[0]) |
                ((unsigned long long)f2bf(acc[1]) << 16) |
                ((unsigned long long)f2bf(acc[2]) << 32) |
                ((unsigned long long)f2bf(acc[3]) << 48);
            *(unsigned long long*)(S + HT_OFF + hcol * HST + hrow) = pk;
        }
        __syncthreads();

        // ---- pass 2 (vertical on H_T): 4 row-subtiles x 2 col-chunks per wave ----
#pragma unroll
        for (int t = 0; t < 4; ++t) {
#pragma unroll
            for (int c2i = 0; c2i < 2; ++c2i) {
                const int c2 = 2 * wv + c2i;
                const int hrow = c2 * 16 + lm;          // H_T row = output col group
                const int kb   = t * 16 + lg * 8;
                const bf16x8 a0 = *(const bf16x8*)(S + HT_OFF + hrow * HST + kb);
                const bf16x8 a1 = *(const bf16x8*)(S + HT_OFF + hrow * HST + kb + 32);
                f32x4 acc = {0.f, 0.f, 0.f, 0.f};
                acc = __builtin_amdgcn_mfma_f32_16x16x32_bf16(a0, b2[0], acc, 0, 0, 0);
                acc = __builtin_amdgcn_mfma_f32_16x16x32_bf16(a1, b2[1], acc, 0, 0, 0);
                if (fi == 0) {
#pragma unroll
                    for (int q = 0; q < 4; ++q) lowsA[t][c2i][q] = acc[q];
                } else {
                    // out row = r0 + t*16 + lm, out cols = c2*16 + lg*4 + q (float4)
                    const int orow = r0 + t * 16 + lm;
                    const int ocol = c2 * 16 + lg * 4;
                    const f32x4 iv = *(const f32x4*)(imgp + orow * 256 + ocol);
                    f32x4 res;
#pragma unroll
                    for (int q = 0; q < 4; ++q) {
                        float hA = iv[q] - lowsA[t][c2i][q];
                        hA = fminf(fmaxf(hA, -1.f), 1.f);
                        float hB = iv[q] - acc[q];
                        hB = fminf(fmaxf(hB, -1.f), 1.f);
                        res[q] = lam * hA + (1.0f - lam) * hB;
                    }
                    float* op = outbase + (((size_t)(p * 12 + plane)) * 65536) +
                                (size_t)orow * 256 + ocol;
                    *(f32x4*)op = res;
                }
            }
        }
        if (fi == 0) __syncthreads();   // protect H_T before filter-B overwrites it
    }
}

extern "C" void kernel_launch(void* const* d_in, const int* in_sizes, int n_in,
                              void* d_out, int out_size, void* d_ws, size_t ws_size,
                              hipStream_t stream) {
    const float* image   = (const float*)d_in[0];   // [4,3,256,256]
    const float* kernels = (const float*)d_in[1];   // [90,45]
    const float* prompt  = (const float*)d_in[2];   // [90]
    const float* lambdap = (const float*)d_in[3];   // [1]
    float* out = (float*)d_out;                     // [32,4,3,256,256]

    int*   ws_idx = (int*)d_ws;
    float* ws_lam = (float*)((char*)d_ws + 256);

    gmix_topk<<<1, 128, 0, stream>>>(prompt, lambdap, ws_idx, ws_lam);
    gmix_mfma<<<1536, 512, LDS_BYTES, stream>>>(image, kernels, ws_idx, ws_lam, out);
}

// Round 3
// 71.141 us; speedup vs baseline: 5.5336x; 1.4063x over previous
//
#include <hip/hip_runtime.h>
#include <hip/hip_bf16.h>
#include <math.h>

typedef __attribute__((ext_vector_type(8))) short bf16x8;
typedef __attribute__((ext_vector_type(4))) float f32x4;

#define HST 136            // H_T row stride (halfs): 272B, 16B-aligned, reads 2-way (free)
// ws layout (bytes)
#define WS_IDX   0         // 64 ints
#define WS_LAM   256       // 1 float
#define WS_FRAG  4096      // 64 fid * 2 variants * 64 lanes * 16 halfs * 2B = 262,144
#define WS_IMG   266240    // 12 planes * 304 rows * 304 cols * 2B = 2,217,984
// total ws used = 2,484,224 bytes

#define PLANE_STRIDE 92416  // 304*304 halfs
#define ROW_STRIDE   304    // halfs

__device__ __forceinline__ unsigned f2bf(float f) {
    unsigned u = __builtin_bit_cast(unsigned, f);
    u += 0x7FFFu + ((u >> 16) & 1u);          // RNE
    return u >> 16;
}

// ---------------- top-k (rank by count) + sigmoid(lambda) ----------------
__global__ __launch_bounds__(128) void gmix_topk(const float* __restrict__ cp,
                                                 const float* __restrict__ lp,
                                                 int* __restrict__ idx,
                                                 float* __restrict__ lam) {
    int i = threadIdx.x;
    if (i < 90) {
        float v = cp[i];
        int rank = 0;
        for (int j = 0; j < 90; ++j) {
            float vj = cp[j];
            rank += (vj > v) || (vj == v && j < i);
        }
        if (rank < 64) idx[rank] = i;
    }
    if (i == 0) lam[0] = 1.0f / (1.0f + expf(-lp[0]));
}

// ---------------- image -> padded bf16 planes in ws ----------------
// [12][304][304] bf16; padded row pr -> img row pr-22 (valid 22..277), col pc -> pc-24 (valid 24..279)
__global__ __launch_bounds__(256) void gmix_prep(const float* __restrict__ img,
                                                 short* __restrict__ wsimg) {
    const int cid = blockIdx.x * 256 + threadIdx.x;          // chunk id (8 halfs each)
    if (cid >= 12 * 304 * 38) return;
    const int plane = cid / (304 * 38);
    const int rr    = cid % (304 * 38);
    const int r     = rr / 38;
    const int ch    = rr % 38;
    uint4 o = {0u, 0u, 0u, 0u};
    const int gr = r - 22;
    if (gr >= 0 && gr < 256 && ch >= 3 && ch < 35) {
        const float* sp = img + (size_t)plane * 65536 + gr * 256 + (ch * 8 - 24);
        const float4 v0 = *(const float4*)sp;
        const float4 v1 = *(const float4*)(sp + 4);
        o.x = f2bf(v0.x) | (f2bf(v0.y) << 16);
        o.y = f2bf(v0.z) | (f2bf(v0.w) << 16);
        o.z = f2bf(v1.x) | (f2bf(v1.y) << 16);
        o.w = f2bf(v1.z) | (f2bf(v1.w) << 16);
    }
    *(uint4*)(wsimg + plane * PLANE_STRIDE + r * ROW_STRIDE + ch * 8) = o;
}

// ---------------- banded tap matrices in MFMA B-fragment layout ----------------
// unit = fid*2 + v; v=0: B1[k][j]=tap[k-j-2] (pass1), v=1: B2[k][j]=tap[k-j] (pass2)
__global__ __launch_bounds__(64) void gmix_frags(const float* __restrict__ kers,
                                                 const int* __restrict__ idx,
                                                 short* __restrict__ frag) {
    const int unit = blockIdx.x;        // 0..127
    const int fid  = unit >> 1;
    const int v    = unit & 1;
    const int f    = idx[fid];
    const int lane = threadIdx.x;
    const int lm   = lane & 15;
    const int lg   = lane >> 4;
    const int shift = v ? 0 : 2;
    short* dst = frag + (unit * 64 + lane) * 16;
#pragma unroll
    for (int ka = 0; ka < 2; ++ka)
#pragma unroll
        for (int e = 0; e < 8; ++e) {
            const int k = ka * 32 + lg * 8 + e;
            const int d = k - lm - shift;
            const float t = (d >= 0 && d < 45) ? kers[f * 45 + d] : 0.f;
            dst[ka * 8 + e] = (short)f2bf(t);
        }
}

// ---------------- MFMA separable conv + clip + mix ----------------
// grid: 32 pairs * 12 planes * 4 bands * 2 col-halves = 3072 blocks, 512 threads
__global__ __launch_bounds__(512, 4) void gmix_mfma(const float* __restrict__ img,
                                                    const short* __restrict__ wsimg,
                                                    const short* __restrict__ frag,
                                                    const float* __restrict__ lamp,
                                                    float* __restrict__ out) {
    __shared__ short HT[128 * HST];     // 34,816 B

    const int tid  = threadIdx.x;
    const int lane = tid & 63;
    const int wv   = tid >> 6;
    const int lm   = lane & 15;
    const int lg   = lane >> 4;

    const int bid   = blockIdx.x;
    const int p     = bid / 96;
    const int rem   = bid % 96;
    const int plane = rem >> 3;
    const int band  = (rem >> 1) & 3;
    const int half  = rem & 1;
    const int r0    = band * 64;

    // window (arow, wc): padded rows r0..r0+111, padded cols half*128..+175
    const short* win  = wsimg + plane * PLANE_STRIDE + r0 * ROW_STRIDE + half * 128;
    const float* imgp = img + (size_t)plane * 65536;
    const float  lam  = lamp[0];

    float lowsA[4][4];

#pragma unroll 1
    for (int fi = 0; fi < 2; ++fi) {
        const int fid = 2 * p + fi;
        const short* fb = frag + (size_t)fid * 2048;   // 2 variants * 64 lanes * 16
        const bf16x8 b1_0 = *(const bf16x8*)(fb + lane * 16);
        const bf16x8 b1_1 = *(const bf16x8*)(fb + lane * 16 + 8);
        const bf16x8 b2_0 = *(const bf16x8*)(fb + 1024 + lane * 16);
        const bf16x8 b2_1 = *(const bf16x8*)(fb + 1024 + lane * 16 + 8);

        if (fi == 1) __syncthreads();   // fi=0 pass2 reads done before overwriting HT

        // ---- pass 1 (horizontal): A from global bf16 ws, C -> H_T in LDS ----
#pragma unroll
        for (int jl = 0; jl < 7; ++jl) {
            const int jj = wv * 7 + jl;          // 0..55
            const int t1 = jj >> 3;              // row-tile 0..6
            const int c  = jj & 7;               // col-chunk 0..7
            const short* ap = win + (t1 * 16 + lm) * ROW_STRIDE + c * 16 + lg * 8;
            const bf16x8 a0 = *(const bf16x8*)ap;
            const bf16x8 a1 = *(const bf16x8*)(ap + 32);
            f32x4 acc = {0.f, 0.f, 0.f, 0.f};
            acc = __builtin_amdgcn_mfma_f32_16x16x32_bf16(a0, b1_0, acc, 0, 0, 0);
            acc = __builtin_amdgcn_mfma_f32_16x16x32_bf16(a1, b1_1, acc, 0, 0, 0);
            // C: H row = t1*16 + lg*4 + q, H col = c*16 + lm -> H_T[col][row]
            const int hrow = t1 * 16 + lg * 4;
            const int hcol = c * 16 + lm;
            const unsigned long long pk =
                (unsigned long long)f2bf(acc[0]) |
                ((unsigned long long)f2bf(acc[1]) << 16) |
                ((unsigned long long)f2bf(acc[2]) << 32) |
                ((unsigned long long)f2bf(acc[3]) << 48);
            *(unsigned long long*)(HT + hcol * HST + hrow) = pk;
        }
        __syncthreads();

        // ---- pass 2 (vertical on H_T): c2 = wv, 4 row-subtiles ----
#pragma unroll
        for (int t = 0; t < 4; ++t) {
            const short* hp = HT + (wv * 16 + lm) * HST + t * 16 + lg * 8;
            const bf16x8 a0 = *(const bf16x8*)hp;
            const bf16x8 a1 = *(const bf16x8*)(hp + 32);
            f32x4 acc = {0.f, 0.f, 0.f, 0.f};
            acc = __builtin_amdgcn_mfma_f32_16x16x32_bf16(a0, b2_0, acc, 0, 0, 0);
            acc = __builtin_amdgcn_mfma_f32_16x16x32_bf16(a1, b2_1, acc, 0, 0, 0);
            if (fi == 0) {
#pragma unroll
                for (int q = 0; q < 4; ++q) lowsA[t][q] = acc[q];
            } else {
                const int orow = r0 + t * 16 + lm;
                const int ocol = half * 128 + wv * 16 + lg * 4;
                const f32x4 iv = *(const f32x4*)(imgp + orow * 256 + ocol);
                f32x4 res;
#pragma unroll
                for (int q = 0; q < 4; ++q) {
                    float hA = iv[q] - lowsA[t][q];
                    hA = fminf(fmaxf(hA, -1.f), 1.f);
                    float hB = iv[q] - acc[q];
                    hB = fminf(fmaxf(hB, -1.f), 1.f);
                    res[q] = lam * hA + (1.0f - lam) * hB;
                }
                float* op = out + ((size_t)(p * 12 + plane) << 16) + orow * 256 + ocol;
                *(f32x4*)op = res;
            }
        }
    }
}

extern "C" void kernel_launch(void* const* d_in, const int* in_sizes, int n_in,
                              void* d_out, int out_size, void* d_ws, size_t ws_size,
                              hipStream_t stream) {
    const float* image   = (const float*)d_in[0];   // [4,3,256,256]
    const float* kernels = (const float*)d_in[1];   // [90,45]
    const float* prompt  = (const float*)d_in[2];   // [90]
    const float* lambdap = (const float*)d_in[3];   // [1]
    float* out = (float*)d_out;                     // [32,4,3,256,256]

    int*   ws_idx  = (int*)d_ws;
    float* ws_lam  = (float*)((char*)d_ws + WS_LAM);
    short* ws_frag = (short*)((char*)d_ws + WS_FRAG);
    short* ws_img  = (short*)((char*)d_ws + WS_IMG);

    gmix_topk<<<1, 128, 0, stream>>>(prompt, lambdap, ws_idx, ws_lam);
    gmix_prep<<<(12 * 304 * 38 + 255) / 256, 256, 0, stream>>>(image, ws_img);
    gmix_frags<<<128, 64, 0, stream>>>(kernels, ws_idx, ws_frag);
    gmix_mfma<<<3072, 512, 0, stream>>>(image, ws_img, ws_frag, ws_lam, out);
}

// Round 5
// 62.282 us; speedup vs baseline: 6.3207x; 1.1422x over previous
//
#include <hip/hip_runtime.h>
#include <hip/hip_bf16.h>
#include <math.h>

typedef __attribute__((ext_vector_type(8))) short bf16x8;
typedef __attribute__((ext_vector_type(4))) float f32x4;

#define HST 136             // H_T row stride (halfs): 272B, 16B-aligned
#define PLANE_STRIDE 92416  // 304*304 halfs
#define ROW_STRIDE   304    // halfs

// ws layout (bytes) — validated round-2 layout
#define WS_IDX   0          // 64 ints
#define WS_LAM   256        // 1 float
#define WS_FRAG  4096       // 64 fid * 2 variants * 64 lanes * 16 halfs * 2B = 262,144
#define WS_IMG   266240     // 12 planes * 304 * 304 * 2B = 2,217,984

#define NB_PREP 542         // ceil(12*304*38 / 256)

__device__ __forceinline__ unsigned f2bf(float f) {
    unsigned u = __builtin_bit_cast(unsigned, f);
    u += 0x7FFFu + ((u >> 16) & 1u);          // RNE
    return u >> 16;
}

// ---------------- top-k (rank by count) + sigmoid(lambda)  [round-2 validated] ----------------
__global__ __launch_bounds__(128) void gmix_topk(const float* __restrict__ cp,
                                                 const float* __restrict__ lp,
                                                 int* __restrict__ idx,
                                                 float* __restrict__ lam) {
    int i = threadIdx.x;
    if (i < 90) {
        float v = cp[i];
        int rank = 0;
        for (int j = 0; j < 90; ++j) {
            float vj = cp[j];
            rank += (vj > v) || (vj == v && j < i);
        }
        if (rank < 64) idx[rank] = i;
    }
    if (i == 0) lam[0] = 1.0f / (1.0f + expf(-lp[0]));
}

// ---------------- prep: image->bf16 padded planes + B-fragment tables ----------------
// blocks [0, NB_PREP): image conversion [round-2 validated body]
// blocks [NB_PREP, NB_PREP+128): frag units [round-2 validated body, reads idx[]]
__global__ __launch_bounds__(256) void gmix_prep(const float* __restrict__ img,
                                                 const float* __restrict__ kers,
                                                 const int* __restrict__ idx,
                                                 short* __restrict__ wsimg,
                                                 short* __restrict__ frag) {
    const int b   = blockIdx.x;
    const int tid = threadIdx.x;
    if (b < NB_PREP) {
        // padded bf16 planes [12][304][304]; row pr -> img row pr-22, col pc -> pc-24
        const int cid = b * 256 + tid;               // 8-half chunks
        if (cid >= 12 * 304 * 38) return;
        const int plane = cid / (304 * 38);
        const int rr    = cid % (304 * 38);
        const int r     = rr / 38;
        const int ch    = rr % 38;
        uint4 o = {0u, 0u, 0u, 0u};
        const int gr = r - 22;
        if (gr >= 0 && gr < 256 && ch >= 3 && ch < 35) {
            const float* sp = img + (size_t)plane * 65536 + gr * 256 + (ch * 8 - 24);
            const float4 v0 = *(const float4*)sp;
            const float4 v1 = *(const float4*)(sp + 4);
            o.x = f2bf(v0.x) | (f2bf(v0.y) << 16);
            o.y = f2bf(v0.z) | (f2bf(v0.w) << 16);
            o.z = f2bf(v1.x) | (f2bf(v1.y) << 16);
            o.w = f2bf(v1.z) | (f2bf(v1.w) << 16);
        }
        *(uint4*)(wsimg + plane * PLANE_STRIDE + r * ROW_STRIDE + ch * 8) = o;
    } else if (tid < 64) {
        // unit = fid*2 + v; v=0: B1[k][j]=tap[k-j-2] (pass1), v=1: B2[k][j]=tap[k-j] (pass2)
        const int unit  = b - NB_PREP;       // 0..127
        const int fid   = unit >> 1;
        const int v     = unit & 1;
        const int f     = idx[fid];
        const int lm    = tid & 15;
        const int lg    = tid >> 4;
        const int shift = v ? 0 : 2;
        short* dst = frag + ((size_t)unit * 64 + tid) * 16;
#pragma unroll
        for (int ka = 0; ka < 2; ++ka)
#pragma unroll
            for (int e = 0; e < 8; ++e) {
                const int k = ka * 32 + lg * 8 + e;
                const int d = k - lm - shift;
                const float t = (d >= 0 && d < 45) ? kers[f * 45 + d] : 0.f;
                dst[ka * 8 + e] = (short)f2bf(t);
            }
    }
}

// ---------------- MFMA separable conv, both filters fused + clip + mix ----------------
// grid: 32 pairs * 12 planes * 4 bands * 2 col-halves = 3072 blocks, 512 threads
__global__ __launch_bounds__(512, 4) void gmix_mfma(const float* __restrict__ img,
                                                    const short* __restrict__ wsimg,
                                                    const short* __restrict__ frag,
                                                    const float* __restrict__ lamp,
                                                    float* __restrict__ out) {
    __shared__ short HT[2][128 * HST];     // 2 x 34,816 B = 69,632 B -> 2 blocks/CU

    const int tid  = threadIdx.x;
    const int lane = tid & 63;
    const int wv   = tid >> 6;
    const int lm   = lane & 15;
    const int lg   = lane >> 4;

    const int bid   = blockIdx.x;
    const int p     = bid / 96;
    const int rem   = bid % 96;
    const int plane = rem >> 3;
    const int band  = (rem >> 1) & 3;
    const int half  = rem & 1;
    const int r0    = band * 64;

    const short* win  = wsimg + plane * PLANE_STRIDE + r0 * ROW_STRIDE + half * 128;
    const float* imgp = img + (size_t)plane * 65536;
    const float  lam  = lamp[0];

    // B-fragments for both filters, both passes
    const short* fbA = frag + (size_t)(2 * p) * 2048;
    const short* fbB = fbA + 2048;
    const bf16x8 bA1_0 = *(const bf16x8*)(fbA + lane * 16);
    const bf16x8 bA1_1 = *(const bf16x8*)(fbA + lane * 16 + 8);
    const bf16x8 bA2_0 = *(const bf16x8*)(fbA + 1024 + lane * 16);
    const bf16x8 bA2_1 = *(const bf16x8*)(fbA + 1024 + lane * 16 + 8);
    const bf16x8 bB1_0 = *(const bf16x8*)(fbB + lane * 16);
    const bf16x8 bB1_1 = *(const bf16x8*)(fbB + lane * 16 + 8);
    const bf16x8 bB2_0 = *(const bf16x8*)(fbB + 1024 + lane * 16);
    const bf16x8 bB2_1 = *(const bf16x8*)(fbB + 1024 + lane * 16 + 8);

    // ---- pass 1 (horizontal, BOTH filters per A-load): C -> H_T (bf16, transposed) ----
#pragma unroll
    for (int jl = 0; jl < 7; ++jl) {
        const int jj = wv * 7 + jl;          // 0..55
        const int t1 = jj >> 3;              // row-tile 0..6
        const int c  = jj & 7;               // col-chunk 0..7
        const short* ap = win + (t1 * 16 + lm) * ROW_STRIDE + c * 16 + lg * 8;
        const bf16x8 a0 = *(const bf16x8*)ap;
        const bf16x8 a1 = *(const bf16x8*)(ap + 32);
        f32x4 accA = {0.f, 0.f, 0.f, 0.f};
        f32x4 accB = {0.f, 0.f, 0.f, 0.f};
        accA = __builtin_amdgcn_mfma_f32_16x16x32_bf16(a0, bA1_0, accA, 0, 0, 0);
        accB = __builtin_amdgcn_mfma_f32_16x16x32_bf16(a0, bB1_0, accB, 0, 0, 0);
        accA = __builtin_amdgcn_mfma_f32_16x16x32_bf16(a1, bA1_1, accA, 0, 0, 0);
        accB = __builtin_amdgcn_mfma_f32_16x16x32_bf16(a1, bB1_1, accB, 0, 0, 0);
        // C: H row = t1*16 + lg*4 + q, H col = c*16 + lm -> H_T[col][row]
        const int off = (c * 16 + lm) * HST + t1 * 16 + lg * 4;
        const unsigned long long pkA =
            (unsigned long long)f2bf(accA[0]) |
            ((unsigned long long)f2bf(accA[1]) << 16) |
            ((unsigned long long)f2bf(accA[2]) << 32) |
            ((unsigned long long)f2bf(accA[3]) << 48);
        const unsigned long long pkB =
            (unsigned long long)f2bf(accB[0]) |
            ((unsigned long long)f2bf(accB[1]) << 16) |
            ((unsigned long long)f2bf(accB[2]) << 32) |
            ((unsigned long long)f2bf(accB[3]) << 48);
        *(unsigned long long*)(&HT[0][off]) = pkA;
        *(unsigned long long*)(&HT[1][off]) = pkB;
    }
    __syncthreads();   // the only barrier

    // ---- pass 2 (vertical on H_T) + clip + mix + store ----
#pragma unroll
    for (int t = 0; t < 4; ++t) {
        const int off = (wv * 16 + lm) * HST + t * 16 + lg * 8;
        const bf16x8 hA0 = *(const bf16x8*)(&HT[0][off]);
        const bf16x8 hA1 = *(const bf16x8*)(&HT[0][off + 32]);
        const bf16x8 hB0 = *(const bf16x8*)(&HT[1][off]);
        const bf16x8 hB1 = *(const bf16x8*)(&HT[1][off + 32]);
        f32x4 aA = {0.f, 0.f, 0.f, 0.f};
        f32x4 aB = {0.f, 0.f, 0.f, 0.f};
        aA = __builtin_amdgcn_mfma_f32_16x16x32_bf16(hA0, bA2_0, aA, 0, 0, 0);
        aB = __builtin_amdgcn_mfma_f32_16x16x32_bf16(hB0, bB2_0, aB, 0, 0, 0);
        aA = __builtin_amdgcn_mfma_f32_16x16x32_bf16(hA1, bA2_1, aA, 0, 0, 0);
        aB = __builtin_amdgcn_mfma_f32_16x16x32_bf16(hB1, bB2_1, aB, 0, 0, 0);

        const int orow = r0 + t * 16 + lm;
        const int ocol = half * 128 + wv * 16 + lg * 4;
        const f32x4 iv = *(const f32x4*)(imgp + orow * 256 + ocol);
        f32x4 res;
#pragma unroll
        for (int q = 0; q < 4; ++q) {
            float hA = iv[q] - aA[q];
            hA = fminf(fmaxf(hA, -1.f), 1.f);
            float hB = iv[q] - aB[q];
            hB = fminf(fmaxf(hB, -1.f), 1.f);
            res[q] = lam * hA + (1.0f - lam) * hB;
        }
        float* op = out + ((size_t)(p * 12 + plane) << 16) + orow * 256 + ocol;
        *(f32x4*)op = res;
    }
}

extern "C" void kernel_launch(void* const* d_in, const int* in_sizes, int n_in,
                              void* d_out, int out_size, void* d_ws, size_t ws_size,
                              hipStream_t stream) {
    const float* image   = (const float*)d_in[0];   // [4,3,256,256]
    const float* kernels = (const float*)d_in[1];   // [90,45]
    const float* prompt  = (const float*)d_in[2];   // [90]
    const float* lambdap = (const float*)d_in[3];   // [1]
    float* out = (float*)d_out;                     // [32,4,3,256,256]

    int*   ws_idx  = (int*)d_ws;
    float* ws_lam  = (float*)((char*)d_ws + WS_LAM);
    short* ws_frag = (short*)((char*)d_ws + WS_FRAG);
    short* ws_img  = (short*)((char*)d_ws + WS_IMG);

    gmix_topk<<<1, 128, 0, stream>>>(prompt, lambdap, ws_idx, ws_lam);
    gmix_prep<<<NB_PREP + 128, 256, 0, stream>>>(image, kernels, ws_idx, ws_img, ws_frag);
    gmix_mfma<<<3072, 512, 0, stream>>>(image, ws_img, ws_frag, ws_lam, out);
}

// Round 7
// 59.199 us; speedup vs baseline: 6.6498x; 1.0521x over previous
//
#include <hip/hip_runtime.h>
#include <hip/hip_bf16.h>
#include <math.h>

typedef __attribute__((ext_vector_type(8))) short bf16x8;
typedef __attribute__((ext_vector_type(4))) float f32x4;

#define HST 136             // H_T row stride (halfs): 272B, 16B-aligned
#define PLANE_STRIDE 92416  // 304*304 halfs
#define ROW_STRIDE   304    // halfs

// ws layout (bytes) — validated layout
#define WS_IDX   0          // 64 ints
#define WS_LAM   256        // 1 float
#define WS_FRAG  4096       // 64 fid * 2 variants * 64 lanes * 16 halfs * 2B = 262,144
#define WS_IMG   266240     // 12 planes * 304 * 304 * 2B = 2,217,984

#define NB_PREP 542         // ceil(12*304*38 / 256)

__device__ __forceinline__ unsigned f2bf(float f) {
    unsigned u = __builtin_bit_cast(unsigned, f);
    u += 0x7FFFu + ((u >> 16) & 1u);          // RNE
    return u >> 16;
}

__device__ __forceinline__ unsigned pk2(float a, float b) {
    // RNE pack of two floats into bf16x2 (validated manual path)
    return f2bf(a) | (f2bf(b) << 16);
}

// ---------------- top-k (rank by count) + sigmoid(lambda)  [validated] ----------------
__global__ __launch_bounds__(128) void gmix_topk(const float* __restrict__ cp,
                                                 const float* __restrict__ lp,
                                                 int* __restrict__ idx,
                                                 float* __restrict__ lam) {
    int i = threadIdx.x;
    if (i < 90) {
        float v = cp[i];
        int rank = 0;
        for (int j = 0; j < 90; ++j) {
            float vj = cp[j];
            rank += (vj > v) || (vj == v && j < i);
        }
        if (rank < 64) idx[rank] = i;
    }
    if (i == 0) lam[0] = 1.0f / (1.0f + expf(-lp[0]));
}

// ---------------- prep: image->bf16 padded planes + B-fragment tables [validated] ----------------
__global__ __launch_bounds__(256) void gmix_prep(const float* __restrict__ img,
                                                 const float* __restrict__ kers,
                                                 const int* __restrict__ idx,
                                                 short* __restrict__ wsimg,
                                                 short* __restrict__ frag) {
    const int b   = blockIdx.x;
    const int tid = threadIdx.x;
    if (b < NB_PREP) {
        const int cid = b * 256 + tid;               // 8-half chunks
        if (cid >= 12 * 304 * 38) return;
        const int plane = cid / (304 * 38);
        const int rr    = cid % (304 * 38);
        const int r     = rr / 38;
        const int ch    = rr % 38;
        uint4 o = {0u, 0u, 0u, 0u};
        const int gr = r - 22;
        if (gr >= 0 && gr < 256 && ch >= 3 && ch < 35) {
            const float* sp = img + (size_t)plane * 65536 + gr * 256 + (ch * 8 - 24);
            const float4 v0 = *(const float4*)sp;
            const float4 v1 = *(const float4*)(sp + 4);
            o.x = pk2(v0.x, v0.y);
            o.y = pk2(v0.z, v0.w);
            o.z = pk2(v1.x, v1.y);
            o.w = pk2(v1.z, v1.w);
        }
        *(uint4*)(wsimg + plane * PLANE_STRIDE + r * ROW_STRIDE + ch * 8) = o;
    } else if (tid < 64) {
        // unit = fid*2 + v; v=0: B1[k][j]=tap[k-j-2] (pass1), v=1: B2[k][j]=tap[k-j] (pass2)
        const int unit  = b - NB_PREP;       // 0..127
        const int fid   = unit >> 1;
        const int v     = unit & 1;
        const int f     = idx[fid];
        const int lm    = tid & 15;
        const int lg    = tid >> 4;
        const int shift = v ? 0 : 2;
        short* dst = frag + ((size_t)unit * 64 + tid) * 16;
#pragma unroll
        for (int ka = 0; ka < 2; ++ka)
#pragma unroll
            for (int e = 0; e < 8; ++e) {
                const int k = ka * 32 + lg * 8 + e;
                const int d = k - lm - shift;
                const float t = (d >= 0 && d < 45) ? kers[f * 45 + d] : 0.f;
                dst[ka * 8 + e] = (short)f2bf(t);
            }
    }
}

// ---------------- MFMA separable conv, barrier-free wave-local structure ----------------
// grid: 32 pairs * 12 planes * 4 bands * 2 col-halves = 3072 blocks, 512 threads.
// wave wv owns col-chunk c = wv for BOTH passes -> pass2 reads only HT data the
// same wave wrote (same-wave DS ordering, no __syncthreads needed).
__global__ __launch_bounds__(512, 4) void gmix_mfma(const float* __restrict__ img,
                                                    const short* __restrict__ wsimg,
                                                    const short* __restrict__ frag,
                                                    const float* __restrict__ lamp,
                                                    float* __restrict__ out) {
    __shared__ short HT[2][128 * HST];     // 69,632 B -> 2 blocks/CU

    const int tid  = threadIdx.x;
    const int lane = tid & 63;
    const int wv   = tid >> 6;
    const int lm   = lane & 15;
    const int lg   = lane >> 4;

    const int bid   = blockIdx.x;
    const int p     = bid / 96;
    const int rem   = bid % 96;
    const int plane = rem >> 3;
    const int band  = (rem >> 1) & 3;
    const int half  = rem & 1;
    const int r0    = band * 64;

    const float* imgp = img + (size_t)plane * 65536;
    const float  lam  = lamp[0];

    // B-fragments for both filters, both passes (8 x b128 from L2)
    const short* fbA = frag + (size_t)(2 * p) * 2048;
    const short* fbB = fbA + 2048;
    const bf16x8 bA1_0 = *(const bf16x8*)(fbA + lane * 16);
    const bf16x8 bA1_1 = *(const bf16x8*)(fbA + lane * 16 + 8);
    const bf16x8 bA2_0 = *(const bf16x8*)(fbA + 1024 + lane * 16);
    const bf16x8 bA2_1 = *(const bf16x8*)(fbA + 1024 + lane * 16 + 8);
    const bf16x8 bB1_0 = *(const bf16x8*)(fbB + lane * 16);
    const bf16x8 bB1_1 = *(const bf16x8*)(fbB + lane * 16 + 8);
    const bf16x8 bB2_0 = *(const bf16x8*)(fbB + 1024 + lane * 16);
    const bf16x8 bB2_1 = *(const bf16x8*)(fbB + 1024 + lane * 16 + 8);

    // ---- pass-1 A tiles: rows (t1*16+lm), cols wv*16 + lg*8 (+32). Batched loads. ----
    const short* abase = wsimg + plane * PLANE_STRIDE + r0 * ROW_STRIDE + half * 128
                       + lm * ROW_STRIDE + wv * 16 + lg * 8;
    bf16x8 a0s[7], a1s[7];
#pragma unroll
    for (int t1 = 0; t1 < 7; ++t1) {
        a0s[t1] = *(const bf16x8*)(abase + t1 * 16 * ROW_STRIDE);
        a1s[t1] = *(const bf16x8*)(abase + t1 * 16 * ROW_STRIDE + 32);
    }

    // ---- pass 1: H tiles -> H_T (bf16, transposed), wave-local column slice ----
    // HT entry: col = wv*16+lm (H col), row = t1*16+lg*4+q (H row)
    short* htw = (short*)&HT[0][0] + (wv * 16 + lm) * HST + lg * 4;
#pragma unroll
    for (int t1 = 0; t1 < 7; ++t1) {
        f32x4 accA = {0.f, 0.f, 0.f, 0.f};
        f32x4 accB = {0.f, 0.f, 0.f, 0.f};
        accA = __builtin_amdgcn_mfma_f32_16x16x32_bf16(a0s[t1], bA1_0, accA, 0, 0, 0);
        accB = __builtin_amdgcn_mfma_f32_16x16x32_bf16(a0s[t1], bB1_0, accB, 0, 0, 0);
        accA = __builtin_amdgcn_mfma_f32_16x16x32_bf16(a1s[t1], bA1_1, accA, 0, 0, 0);
        accB = __builtin_amdgcn_mfma_f32_16x16x32_bf16(a1s[t1], bB1_1, accB, 0, 0, 0);
        uint2 pkA, pkB;
        pkA.x = pk2(accA[0], accA[1]);
        pkA.y = pk2(accA[2], accA[3]);
        pkB.x = pk2(accB[0], accB[1]);
        pkB.y = pk2(accB[2], accB[3]);
        *(uint2*)(htw + t1 * 16) = pkA;
        *(uint2*)(htw + 128 * HST + t1 * 16) = pkB;
    }

    // ---- prefetch iv (f32 image) for the combine while LDS writes land ----
    const int ocol = half * 128 + wv * 16 + lg * 4;
    f32x4 ivs[4];
#pragma unroll
    for (int t = 0; t < 4; ++t)
        ivs[t] = *(const f32x4*)(imgp + (r0 + t * 16 + lm) * 256 + ocol);

    // ---- pass 2 (vertical on own H_T slice) + clip + mix + store ----
    const short* htr = (const short*)&HT[0][0] + (wv * 16 + lm) * HST + lg * 8;
#pragma unroll
    for (int t = 0; t < 4; ++t) {
        const bf16x8 hA0 = *(const bf16x8*)(htr + t * 16);
        const bf16x8 hA1 = *(const bf16x8*)(htr + t * 16 + 32);
        const bf16x8 hB0 = *(const bf16x8*)(htr + 128 * HST + t * 16);
        const bf16x8 hB1 = *(const bf16x8*)(htr + 128 * HST + t * 16 + 32);
        f32x4 aA = {0.f, 0.f, 0.f, 0.f};
        f32x4 aB = {0.f, 0.f, 0.f, 0.f};
        aA = __builtin_amdgcn_mfma_f32_16x16x32_bf16(hA0, bA2_0, aA, 0, 0, 0);
        aB = __builtin_amdgcn_mfma_f32_16x16x32_bf16(hB0, bB2_0, aB, 0, 0, 0);
        aA = __builtin_amdgcn_mfma_f32_16x16x32_bf16(hA1, bA2_1, aA, 0, 0, 0);
        aB = __builtin_amdgcn_mfma_f32_16x16x32_bf16(hB1, bB2_1, aB, 0, 0, 0);

        f32x4 res;
#pragma unroll
        for (int q = 0; q < 4; ++q) {
            float hA = ivs[t][q] - aA[q];
            hA = fminf(fmaxf(hA, -1.f), 1.f);
            float hB = ivs[t][q] - aB[q];
            hB = fminf(fmaxf(hB, -1.f), 1.f);
            res[q] = lam * hA + (1.0f - lam) * hB;
        }
        float* op = out + ((size_t)(p * 12 + plane) << 16) + (r0 + t * 16 + lm) * 256 + ocol;
        *(f32x4*)op = res;
    }
}

extern "C" void kernel_launch(void* const* d_in, const int* in_sizes, int n_in,
                              void* d_out, int out_size, void* d_ws, size_t ws_size,
                              hipStream_t stream) {
    const float* image   = (const float*)d_in[0];   // [4,3,256,256]
    const float* kernels = (const float*)d_in[1];   // [90,45]
    const float* prompt  = (const float*)d_in[2];   // [90]
    const float* lambdap = (const float*)d_in[3];   // [1]
    float* out = (float*)d_out;                     // [32,4,3,256,256]

    int*   ws_idx  = (int*)d_ws;
    float* ws_lam  = (float*)((char*)d_ws + WS_LAM);
    short* ws_frag = (short*)((char*)d_ws + WS_FRAG);
    short* ws_img  = (short*)((char*)d_ws + WS_IMG);

    gmix_topk<<<1, 128, 0, stream>>>(prompt, lambdap, ws_idx, ws_lam);
    gmix_prep<<<NB_PREP + 128, 256, 0, stream>>>(image, kernels, ws_idx, ws_img, ws_frag);
    gmix_mfma<<<3072, 512, 0, stream>>>(image, ws_img, ws_frag, ws_lam, out);
}

// Round 8
// 53.819 us; speedup vs baseline: 7.3145x; 1.1000x over previous
//
#include <hip/hip_runtime.h>
#include <hip/hip_bf16.h>
#include <math.h>

typedef __attribute__((ext_vector_type(8))) short bf16x8;
typedef __attribute__((ext_vector_type(4))) float f32x4;

#define HST 136             // H_T row stride (halfs): 272B, 16B-aligned
#define AST 184             // A-LDS row stride (halfs): 368B, 16B-aligned, 2-way banks
#define PLANE_STRIDE 92416  // 304*304 halfs
#define ROW_STRIDE   304    // halfs

// LDS layout (halfs): A [112*184 = 20608] then HT[2][128*136]
#define LDS_A_HALFS  20608
#define LDS_HT_HALFS (128 * HST)
#define LDS_BYTES    ((LDS_A_HALFS + 2 * LDS_HT_HALFS) * 2)   // 110,848 B

// ws layout (bytes) — validated layout
#define WS_IDX   0          // 64 ints
#define WS_LAM   256        // 1 float
#define WS_FRAG  4096       // 64 fid * 2 variants * 64 lanes * 16 halfs * 2B = 262,144
#define WS_IMG   266240     // 12 planes * 304 * 304 * 2B = 2,217,984

#define NB_PREP 542         // ceil(12*304*38 / 256)

__device__ __forceinline__ unsigned f2bf(float f) {
    unsigned u = __builtin_bit_cast(unsigned, f);
    u += 0x7FFFu + ((u >> 16) & 1u);          // RNE
    return u >> 16;
}

__device__ __forceinline__ unsigned pk2(float a, float b) {
    return f2bf(a) | (f2bf(b) << 16);
}

// ---------------- top-k (rank by count) + sigmoid(lambda)  [validated] ----------------
__global__ __launch_bounds__(128) void gmix_topk(const float* __restrict__ cp,
                                                 const float* __restrict__ lp,
                                                 int* __restrict__ idx,
                                                 float* __restrict__ lam) {
    int i = threadIdx.x;
    if (i < 90) {
        float v = cp[i];
        int rank = 0;
        for (int j = 0; j < 90; ++j) {
            float vj = cp[j];
            rank += (vj > v) || (vj == v && j < i);
        }
        if (rank < 64) idx[rank] = i;
    }
    if (i == 0) lam[0] = 1.0f / (1.0f + expf(-lp[0]));
}

// ---------------- prep: image->bf16 padded planes + B-fragment tables [validated] ----------------
__global__ __launch_bounds__(256) void gmix_prep(const float* __restrict__ img,
                                                 const float* __restrict__ kers,
                                                 const int* __restrict__ idx,
                                                 short* __restrict__ wsimg,
                                                 short* __restrict__ frag) {
    const int b   = blockIdx.x;
    const int tid = threadIdx.x;
    if (b < NB_PREP) {
        const int cid = b * 256 + tid;               // 8-half chunks
        if (cid >= 12 * 304 * 38) return;
        const int plane = cid / (304 * 38);
        const int rr    = cid % (304 * 38);
        const int r     = rr / 38;
        const int ch    = rr % 38;
        uint4 o = {0u, 0u, 0u, 0u};
        const int gr = r - 22;
        if (gr >= 0 && gr < 256 && ch >= 3 && ch < 35) {
            const float* sp = img + (size_t)plane * 65536 + gr * 256 + (ch * 8 - 24);
            const float4 v0 = *(const float4*)sp;
            const float4 v1 = *(const float4*)(sp + 4);
            o.x = pk2(v0.x, v0.y);
            o.y = pk2(v0.z, v0.w);
            o.z = pk2(v1.x, v1.y);
            o.w = pk2(v1.z, v1.w);
        }
        *(uint4*)(wsimg + plane * PLANE_STRIDE + r * ROW_STRIDE + ch * 8) = o;
    } else if (tid < 64) {
        // unit = fid*2 + v; v=0: B1[k][j]=tap[k-j-2] (pass1), v=1: B2[k][j]=tap[k-j] (pass2)
        const int unit  = b - NB_PREP;       // 0..127
        const int fid   = unit >> 1;
        const int v     = unit & 1;
        const int f     = idx[fid];
        const int lm    = tid & 15;
        const int lg    = tid >> 4;
        const int shift = v ? 0 : 2;
        short* dst = frag + ((size_t)unit * 64 + tid) * 16;
#pragma unroll
        for (int ka = 0; ka < 2; ++ka)
#pragma unroll
            for (int e = 0; e < 8; ++e) {
                const int k = ka * 32 + lg * 8 + e;
                const int d = k - lm - shift;
                const float t = (d >= 0 && d < 45) ? kers[f * 45 + d] : 0.f;
                dst[ka * 8 + e] = (short)f2bf(t);
            }
    }
}

// ---------------- MFMA separable conv: 4 pairs per block, A staged in LDS ----------------
// grid: 8 pair-groups * 12 planes * 4 bands * 2 col-halves = 768 blocks, 512 threads.
// Wave-local HT slices (validated): no barriers in the pair loop.
__global__ __launch_bounds__(512, 2) void gmix_mfma(const float* __restrict__ img,
                                                    const short* __restrict__ wsimg,
                                                    const short* __restrict__ frag,
                                                    const float* __restrict__ lamp,
                                                    float* __restrict__ out) {
    extern __shared__ short S[];               // A [112][AST] ++ HT[2][128*HST]
    short* A  = S;
    short* HT = S + LDS_A_HALFS;

    const int tid  = threadIdx.x;
    const int lane = tid & 63;
    const int wv   = tid >> 6;
    const int lm   = lane & 15;
    const int lg   = lane >> 4;

    const int bid   = blockIdx.x;
    const int pg    = bid / 96;                // pair-group 0..7  (pairs 4pg..4pg+3)
    const int rem   = bid % 96;
    const int plane = rem >> 3;
    const int band  = (rem >> 1) & 3;
    const int half  = rem & 1;
    const int r0    = band * 64;

    const float* imgp = img + (size_t)plane * 65536;
    const float  lam  = lamp[0];

    // ---- stage A window: padded rows r0..r0+111, padded cols half*128..+175 ----
    {
        const short* src = wsimg + plane * PLANE_STRIDE + r0 * ROW_STRIDE + half * 128;
#pragma unroll
        for (int s = 0; s < 5; ++s) {
            const int it = s * 512 + tid;            // 112 rows * 22 chunks = 2464
            if (it < 112 * 22) {
                const int wr  = it / 22;
                const int wc8 = it % 22;
                const uint4 v = *(const uint4*)(src + wr * ROW_STRIDE + wc8 * 8);
                *(uint4*)(A + wr * AST + wc8 * 8) = v;
            }
        }
    }

    // ---- iv (f32 image) for the combine: pair-invariant, hoisted ----
    const int ocol = half * 128 + wv * 16 + lg * 4;
    f32x4 ivs[4];
#pragma unroll
    for (int t = 0; t < 4; ++t)
        ivs[t] = *(const f32x4*)(imgp + (r0 + t * 16 + lm) * 256 + ocol);

    __syncthreads();   // A fully staged (the only barrier)

    // wave-local LDS bases (same for every pair)
    const short* arow = A + lm * AST + wv * 16 + lg * 8;   // + t1*16*AST
    short*       htw  = HT + (wv * 16 + lm) * HST + lg * 4;
    const short* htr  = HT + (wv * 16 + lm) * HST + lg * 8;

#pragma unroll 1
    for (int i = 0; i < 4; ++i) {
        const int p = pg * 4 + i;

        // B-fragments for both filters, both passes (8 x b128 from L2)
        const short* fbA = frag + (size_t)(2 * p) * 2048;
        const short* fbB = fbA + 2048;
        const bf16x8 bA1_0 = *(const bf16x8*)(fbA + lane * 16);
        const bf16x8 bA1_1 = *(const bf16x8*)(fbA + lane * 16 + 8);
        const bf16x8 bA2_0 = *(const bf16x8*)(fbA + 1024 + lane * 16);
        const bf16x8 bA2_1 = *(const bf16x8*)(fbA + 1024 + lane * 16 + 8);
        const bf16x8 bB1_0 = *(const bf16x8*)(fbB + lane * 16);
        const bf16x8 bB1_1 = *(const bf16x8*)(fbB + lane * 16 + 8);
        const bf16x8 bB2_0 = *(const bf16x8*)(fbB + 1024 + lane * 16);
        const bf16x8 bB2_1 = *(const bf16x8*)(fbB + 1024 + lane * 16 + 8);

        // ---- pass 1: A from LDS, H -> H_T (bf16, transposed, wave-local slice) ----
#pragma unroll
        for (int t1 = 0; t1 < 7; ++t1) {
            const bf16x8 a0 = *(const bf16x8*)(arow + t1 * 16 * AST);
            const bf16x8 a1 = *(const bf16x8*)(arow + t1 * 16 * AST + 32);
            f32x4 accA = {0.f, 0.f, 0.f, 0.f};
            f32x4 accB = {0.f, 0.f, 0.f, 0.f};
            accA = __builtin_amdgcn_mfma_f32_16x16x32_bf16(a0, bA1_0, accA, 0, 0, 0);
            accB = __builtin_amdgcn_mfma_f32_16x16x32_bf16(a0, bB1_0, accB, 0, 0, 0);
            accA = __builtin_amdgcn_mfma_f32_16x16x32_bf16(a1, bA1_1, accA, 0, 0, 0);
            accB = __builtin_amdgcn_mfma_f32_16x16x32_bf16(a1, bB1_1, accB, 0, 0, 0);
            uint2 pkA, pkB;
            pkA.x = pk2(accA[0], accA[1]);
            pkA.y = pk2(accA[2], accA[3]);
            pkB.x = pk2(accB[0], accB[1]);
            pkB.y = pk2(accB[2], accB[3]);
            *(uint2*)(htw + t1 * 16) = pkA;
            *(uint2*)(htw + LDS_HT_HALFS + t1 * 16) = pkB;
        }

        // ---- pass 2 (vertical on own H_T slice) + clip + mix + store ----
        float* outp = out + ((size_t)(p * 12 + plane) << 16);
#pragma unroll
        for (int t = 0; t < 4; ++t) {
            const bf16x8 hA0 = *(const bf16x8*)(htr + t * 16);
            const bf16x8 hA1 = *(const bf16x8*)(htr + t * 16 + 32);
            const bf16x8 hB0 = *(const bf16x8*)(htr + LDS_HT_HALFS + t * 16);
            const bf16x8 hB1 = *(const bf16x8*)(htr + LDS_HT_HALFS + t * 16 + 32);
            f32x4 aA = {0.f, 0.f, 0.f, 0.f};
            f32x4 aB = {0.f, 0.f, 0.f, 0.f};
            aA = __builtin_amdgcn_mfma_f32_16x16x32_bf16(hA0, bA2_0, aA, 0, 0, 0);
            aB = __builtin_amdgcn_mfma_f32_16x16x32_bf16(hB0, bB2_0, aB, 0, 0, 0);
            aA = __builtin_amdgcn_mfma_f32_16x16x32_bf16(hA1, bA2_1, aA, 0, 0, 0);
            aB = __builtin_amdgcn_mfma_f32_16x16x32_bf16(hB1, bB2_1, aB, 0, 0, 0);

            f32x4 res;
#pragma unroll
            for (int q = 0; q < 4; ++q) {
                float hA = ivs[t][q] - aA[q];
                hA = fminf(fmaxf(hA, -1.f), 1.f);
                float hB = ivs[t][q] - aB[q];
                hB = fminf(fmaxf(hB, -1.f), 1.f);
                res[q] = lam * hA + (1.0f - lam) * hB;
            }
            *(f32x4*)(outp + (r0 + t * 16 + lm) * 256 + ocol) = res;
        }
    }
}

extern "C" void kernel_launch(void* const* d_in, const int* in_sizes, int n_in,
                              void* d_out, int out_size, void* d_ws, size_t ws_size,
                              hipStream_t stream) {
    const float* image   = (const float*)d_in[0];   // [4,3,256,256]
    const float* kernels = (const float*)d_in[1];   // [90,45]
    const float* prompt  = (const float*)d_in[2];   // [90]
    const float* lambdap = (const float*)d_in[3];   // [1]
    float* out = (float*)d_out;                     // [32,4,3,256,256]

    int*   ws_idx  = (int*)d_ws;
    float* ws_lam  = (float*)((char*)d_ws + WS_LAM);
    short* ws_frag = (short*)((char*)d_ws + WS_FRAG);
    short* ws_img  = (short*)((char*)d_ws + WS_IMG);

    gmix_topk<<<1, 128, 0, stream>>>(prompt, lambdap, ws_idx, ws_lam);
    gmix_prep<<<NB_PREP + 128, 256, 0, stream>>>(image, kernels, ws_idx, ws_img, ws_frag);
    gmix_mfma<<<768, 512, LDS_BYTES, stream>>>(image, ws_img, ws_frag, ws_lam, out);
}